// Round 6
// baseline (523.624 us; speedup 1.0000x reference)
//
#include <hip/hip_runtime.h>

typedef _Float16 f16x8 __attribute__((ext_vector_type(8)));
typedef float    f32x4 __attribute__((ext_vector_type(4)));
typedef unsigned short u16;

#define VOC   128000
#define TOPIC 512
#define EMB   1024
#define BATCH 1024
#define ROWB  128   // LDS row = 64 f16 = 128 B

__device__ __forceinline__ int swz(int row, int kbyte) {
    return row * ROWB + (kbyte ^ ((row & 7) << 4));
}
__device__ __forceinline__ int xcd_swz(int bid, int nwg) {
    return (bid & 7) * (nwg >> 3) + (bid >> 3);
}
union H2U { _Float16 h; u16 u; };

#define SBAR() asm volatile("s_barrier" ::: "memory")
#define WVM0() asm volatile("s_waitcnt vmcnt(0)" ::: "memory")
#define WVM6() asm volatile("s_waitcnt vmcnt(6)" ::: "memory")
#define WVM8() asm volatile("s_waitcnt vmcnt(8)" ::: "memory")
#define WLG0() asm volatile("s_waitcnt lgkmcnt(0)" ::: "memory")

// ---------------------------------------------------------------------------
// K0: betat f32 -> f16 (into the ws MB that xst later overwrites with xsT)
// ---------------------------------------------------------------------------
__global__ void cvt_betat_kernel(const float* __restrict__ betat, u16* __restrict__ bt16) {
    const size_t g = (size_t)blockIdx.x * 256 + threadIdx.x;
    const float4* src = reinterpret_cast<const float4*>(betat) + g * 2;
    float4 a = src[0], b = src[1];
    f16x8 h;
    h[0]=(_Float16)a.x; h[1]=(_Float16)a.y; h[2]=(_Float16)a.z; h[3]=(_Float16)a.w;
    h[4]=(_Float16)b.x; h[5]=(_Float16)b.y; h[6]=(_Float16)b.z; h[7]=(_Float16)b.w;
    *(reinterpret_cast<f16x8*>(bt16) + g) = h;
}

// ---------------------------------------------------------------------------
// K1: W = beta0 @ betat16^T; E=f16(exp(W)); col-sums. 128x256 tile, BK=64.
// 3-deep pipeline: B 3 LDS bufs (gload_lds), A 2 reg sets; counted vmcnt(8).
// ---------------------------------------------------------------------------
__global__ __launch_bounds__(512, 2) void gemm1_kernel(
    const float* __restrict__ beta0, const u16* __restrict__ bt16,
    u16* __restrict__ Eg, size_t TSTR, int RSTR, float* __restrict__ sg)
{
    __shared__ char lds[131072];   // A: 2x16KB @0, B: 3x32KB @32768

    const int tid  = threadIdx.x;
    const int lane = tid & 63;
    const int wid  = tid >> 6;            // 8 waves: 2 (v) x 4 (t)
    const int wr = wid >> 2, wc = wid & 3;
    const int lr = lane & 15, lk = lane >> 4;
    const int srow8  = lane >> 3;
    const int schunk = ((lane & 7) ^ srow8) * 8;

    const int bid  = xcd_swz(blockIdx.x, gridDim.x);
    const int t0   = (bid & 1) * 256;
    const int tile = bid >> 1;
    const int v0   = tile * 128;

    const int arow = tid >> 2;
    const int asp  = (tid & 3) * 2;

    f32x4 acc[4][4] = {};
    float4 rAa[4], rAb[4];

    const float4* aBase = reinterpret_cast<const float4*>(
        beta0 + (size_t)(v0 + arow) * EMB);

#define G1_LOADA(RA, kt) { \
    const float4* gp = aBase + (kt) * 16 + asp * 2; \
    RA[0] = gp[0]; RA[1] = gp[1]; RA[2] = gp[2]; RA[3] = gp[3]; }

    auto issueB = [&](int kt) {
        const u16* bsrc = bt16 + (size_t)(t0 + wid * 8 + srow8) * EMB + kt * 64 + schunk;
        char* dstb = lds + 32768 + (kt % 3) * 32768;
        #pragma unroll
        for (int p = 0; p < 4; ++p)
            __builtin_amdgcn_global_load_lds(
                (const __attribute__((address_space(1))) unsigned int*)(bsrc + (size_t)p * 64 * EMB),
                (__attribute__((address_space(3))) unsigned int*)(dstb + (p * 64 + wid * 8) * ROWB),
                16, 0, 0);
    };

    issueB(0); G1_LOADA(rAa, 0);
    issueB(1); G1_LOADA(rAb, 1);

#define G1_STEP(kt, RA) { \
    SBAR();                       /* MFMA(kt-1) done everywhere */ \
    if ((kt) < 15) { WVM8(); } else { WVM0(); }  /* tile kt landed; kt+1 in flight */ \
    char* ldsA = lds + ((kt) & 1) * 16384; \
    char* ldsB = lds + 32768 + ((kt) % 3) * 32768; \
    { f16x8 h; \
      h[0]=(_Float16)RA[0].x; h[1]=(_Float16)RA[0].y; h[2]=(_Float16)RA[0].z; h[3]=(_Float16)RA[0].w; \
      h[4]=(_Float16)RA[1].x; h[5]=(_Float16)RA[1].y; h[6]=(_Float16)RA[1].z; h[7]=(_Float16)RA[1].w; \
      *reinterpret_cast<f16x8*>(ldsA + swz(arow, asp * 16)) = h; \
      f16x8 h2; \
      h2[0]=(_Float16)RA[2].x; h2[1]=(_Float16)RA[2].y; h2[2]=(_Float16)RA[2].z; h2[3]=(_Float16)RA[2].w; \
      h2[4]=(_Float16)RA[3].x; h2[5]=(_Float16)RA[3].y; h2[6]=(_Float16)RA[3].z; h2[7]=(_Float16)RA[3].w; \
      *reinterpret_cast<f16x8*>(ldsA + swz(arow, (asp + 1) * 16)) = h2; } \
    if ((kt) + 2 < 16) { issueB((kt) + 2); G1_LOADA(RA, (kt) + 2); } \
    WLG0(); \
    SBAR();                       /* stage visible; kt+1/kt+2 loads stay in flight */ \
    _Pragma("unroll") \
    for (int ks = 0; ks < 2; ++ks) { \
        f16x8 af[4], bf[4]; \
        _Pragma("unroll") \
        for (int m = 0; m < 4; ++m) \
            af[m] = *reinterpret_cast<const f16x8*>(ldsA + swz(wr * 64 + m * 16 + lr, ks * 64 + lk * 16)); \
        _Pragma("unroll") \
        for (int n = 0; n < 4; ++n) \
            bf[n] = *reinterpret_cast<const f16x8*>(ldsB + swz(wc * 64 + n * 16 + lr, ks * 64 + lk * 16)); \
        _Pragma("unroll") \
        for (int m = 0; m < 4; ++m) \
            _Pragma("unroll") \
            for (int n = 0; n < 4; ++n) \
                acc[m][n] = __builtin_amdgcn_mfma_f32_16x16x32_f16( \
                    af[m], bf[n], acc[m][n], 0, 0, 0); \
    } }

    for (int k2 = 0; k2 < 8; ++k2) {
        const int kt0 = 2 * k2;
        G1_STEP(kt0,     rAa);
        G1_STEP(kt0 + 1, rAb);
    }

    // Epilogue: exp -> LDS repack -> E write + col sums
    __syncthreads();
    u16* ldsE = reinterpret_cast<u16*>(lds);   // 64 x 264 u16
    float csum = 0.f;
    #pragma unroll
    for (int c = 0; c < 2; ++c) {
        if (wr == c) {
            #pragma unroll
            for (int m = 0; m < 4; ++m)
              #pragma unroll
              for (int n = 0; n < 4; ++n)
                #pragma unroll
                for (int r = 0; r < 4; ++r) {
                    const int row = m * 16 + lk * 4 + r;
                    const int col = wc * 64 + n * 16 + lr;
                    H2U cv; cv.h = (_Float16)__expf(acc[m][n][r]);
                    ldsE[row * 264 + col] = cv.u;
                }
        }
        __syncthreads();
        {
            const int row8 = tid >> 3, seg = tid & 7;
            const int4* srcp = reinterpret_cast<const int4*>(&ldsE[row8 * 264 + seg * 32]);
            u16* dst = Eg + tile * TSTR + (size_t)(c * 64 + row8) * RSTR + t0 + seg * 32;
            int4 v0v = srcp[0], v1v = srcp[1], v2v = srcp[2], v3v = srcp[3];
            int4* dp = reinterpret_cast<int4*>(dst);
            dp[0] = v0v; dp[1] = v1v; dp[2] = v2v; dp[3] = v3v;
        }
        if (tid < 256) {
            float s = 0.f;
            for (int r = 0; r < 64; ++r) { H2U cv; cv.u = ldsE[r * 264 + tid]; s += (float)cv.h; }
            csum += s;
        }
        __syncthreads();
    }
    if (tid < 256) atomicAdd(sg + t0 + tid, csum);
}

// ---------------------------------------------------------------------------
// K2: xsT[b][t] = f16( x[t][b] * 65536 / s[t] )
// ---------------------------------------------------------------------------
__global__ void xst_kernel(const float* __restrict__ x, const float* __restrict__ s,
                           u16* __restrict__ xsT)
{
    __shared__ float tile[32][33];
    const int b0 = blockIdx.x * 32, t0 = blockIdx.y * 32;
    const int tx = threadIdx.x, ty = threadIdx.y;
    tile[ty][tx] = x[(size_t)(t0 + ty) * BATCH + b0 + tx];
    __syncthreads();
    const float sc = 65536.0f / s[t0 + tx];
    H2U cv; cv.h = (_Float16)(tile[tx][ty] * sc);
    xsT[(size_t)(b0 + ty) * TOPIC + t0 + tx] = cv.u;
}

// ---------------------------------------------------------------------------
// K3a: out = (E @ xsT^T) * 2^-16 ; 128x256 tile; both operands gload_lds;
//      3-deep pipeline (3 bufs each), counted vmcnt(6).
// ---------------------------------------------------------------------------
__global__ __launch_bounds__(512, 2) void gemm2a_kernel(
    const u16* __restrict__ Eg, size_t TSTR, int RSTR,
    const u16* __restrict__ xsT, float* __restrict__ out, int c0, int nch)
{
    __shared__ char lds[147456];   // A: 3x16KB @0, B: 3x32KB @49152

    const int tid  = threadIdx.x;
    const int lane = tid & 63;
    const int wid  = tid >> 6;
    const int wr = wid >> 2, wc = wid & 3;
    const int lr = lane & 15, lk = lane >> 4;
    const int srow8  = lane >> 3;
    const int schunk = ((lane & 7) ^ srow8) * 8;

    const int bid   = xcd_swz(blockIdx.x, gridDim.x);
    const int tile  = bid / nch;
    const int chunk = bid % nch;
    const int b0    = c0 + chunk * 256;
    const int v0    = tile * 128;
    const u16* Et   = Eg + tile * TSTR;

    f32x4 acc[4][4] = {};

    auto issueAB = [&](int kt) {
        const int k0 = kt * 64;
        char* dA = lds + (kt % 3) * 16384;
        char* dB = lds + 49152 + (kt % 3) * 32768;
        #pragma unroll
        for (int p = 0; p < 2; ++p) {
            const int rbase = p * 64 + wid * 8;
            __builtin_amdgcn_global_load_lds(
                (const __attribute__((address_space(1))) unsigned int*)
                    (Et + (size_t)(rbase + srow8) * RSTR + k0 + schunk),
                (__attribute__((address_space(3))) unsigned int*)(dA + rbase * ROWB),
                16, 0, 0);
        }
        #pragma unroll
        for (int p = 0; p < 4; ++p) {
            const int rbase = p * 64 + wid * 8;
            __builtin_amdgcn_global_load_lds(
                (const __attribute__((address_space(1))) unsigned int*)
                    (xsT + (size_t)(b0 + rbase + srow8) * TOPIC + k0 + schunk),
                (__attribute__((address_space(3))) unsigned int*)(dB + rbase * ROWB),
                16, 0, 0);
        }
    };

    issueAB(0);
    issueAB(1);

    for (int kt = 0; kt < TOPIC / 64; ++kt) {
        char* ldsA = lds + (kt % 3) * 16384;
        char* ldsB = lds + 49152 + (kt % 3) * 32768;

        SBAR();                                 // MFMA(kt-1) done everywhere
        if (kt < TOPIC / 64 - 1) { WVM6(); } else { WVM0(); }   // tile kt landed
        if (kt + 2 < TOPIC / 64) issueAB(kt + 2);
        SBAR();                                 // all waves confirmed tile kt
        #pragma unroll
        for (int ks = 0; ks < 2; ++ks) {
            f16x8 af[4], bf[4];
            #pragma unroll
            for (int m = 0; m < 4; ++m)
                af[m] = *reinterpret_cast<const f16x8*>(ldsA + swz(wr * 64 + m * 16 + lr, ks * 64 + lk * 16));
            #pragma unroll
            for (int n = 0; n < 4; ++n)
                bf[n] = *reinterpret_cast<const f16x8*>(ldsB + swz(wc * 64 + n * 16 + lr, ks * 64 + lk * 16));
            #pragma unroll
            for (int m = 0; m < 4; ++m)
                #pragma unroll
                for (int n = 0; n < 4; ++n)
                    acc[m][n] = __builtin_amdgcn_mfma_f32_16x16x32_f16(
                        af[m], bf[n], acc[m][n], 0, 0, 0);
        }
    }

    #pragma unroll
    for (int m = 0; m < 4; ++m)
      #pragma unroll
      for (int n = 0; n < 4; ++n)
        #pragma unroll
        for (int r = 0; r < 4; ++r) {
            const int row = wr * 64 + m * 16 + lk * 4 + r;
            const int col = wc * 64 + n * 16 + lr;
            out[(size_t)(v0 + row) * BATCH + b0 + col] = acc[m][n][r] * 0x1p-16f;
        }
}

// ---------------------------------------------------------------------------
// K3b (fallback): cols 0..255 (these bytes ARE E). Preload own E to regs,
// fence, then 2-phase dbuf xsT staging.
// ---------------------------------------------------------------------------
__global__ __launch_bounds__(512, 2) void gemm2b_kernel(
    const u16* __restrict__ EgBase,   // == (u16*)out, RSTR=2048, TSTR=262144
    const u16* __restrict__ xsT, float* __restrict__ out)
{
    __shared__ char lds[65536];       // B dbuf: 2 x 32KB

    const int tid  = threadIdx.x;
    const int lane = tid & 63;
    const int wid  = tid >> 6;        // 8 waves: 2 (rows) x 4 (cols)
    const int wr = wid >> 2, wc = wid & 3;
    const int lr = lane & 15, lk = lane >> 4;

    const int bid  = xcd_swz(blockIdx.x, gridDim.x);
    const int tile = bid >> 1;
    const int h    = bid & 1;
    const u16* Et  = EgBase + (size_t)tile * 262144;

    f16x8 af[2][16];
    #pragma unroll
    for (int m = 0; m < 2; ++m) {
        const int row = h * 64 + wr * 32 + m * 16 + lr;
        #pragma unroll
        for (int kb = 0; kb < 16; ++kb)
            af[m][kb] = *reinterpret_cast<const f16x8*>(
                Et + (size_t)row * 2048 + kb * 32 + lk * 8);
    }
    WVM0();
    __syncthreads();   // all E reads complete before any out write below

    int4 rX[4];
    auto loadX = [&](int kt) {
        const int srow = tid >> 1;
        const int sp   = (tid & 1) * 4;
        const int4* gv = reinterpret_cast<const int4*>(
            xsT + (size_t)srow * TOPIC + kt * 64 + sp * 8);
        rX[0] = gv[0]; rX[1] = gv[1]; rX[2] = gv[2]; rX[3] = gv[3];
    };
    loadX(0);

    f32x4 acc[2][4] = {};
    for (int kt = 0; kt < 8; ++kt) {
        const int cur = kt & 1;
        char* ldsB = lds + cur * 32768;

        SBAR();
        WVM0();
        {
            const int srow = tid >> 1;
            const int sp   = (tid & 1) * 4;
            *reinterpret_cast<int4*>(ldsB + swz(srow, (sp + 0) * 16)) = rX[0];
            *reinterpret_cast<int4*>(ldsB + swz(srow, (sp + 1) * 16)) = rX[1];
            *reinterpret_cast<int4*>(ldsB + swz(srow, (sp + 2) * 16)) = rX[2];
            *reinterpret_cast<int4*>(ldsB + swz(srow, (sp + 3) * 16)) = rX[3];
        }
        if (kt + 1 < 8) loadX(kt + 1);
        WLG0();
        SBAR();
        #pragma unroll
        for (int kk = 0; kk < 2; ++kk) {
            f16x8 bf[4];
            #pragma unroll
            for (int n = 0; n < 4; ++n)
                bf[n] = *reinterpret_cast<const f16x8*>(ldsB + swz(wc * 64 + n * 16 + lr, kk * 64 + lk * 16));
            #pragma unroll
            for (int m = 0; m < 2; ++m)
                #pragma unroll
                for (int n = 0; n < 4; ++n)
                    acc[m][n] = __builtin_amdgcn_mfma_f32_16x16x32_f16(
                        af[m][kt * 2 + kk], bf[n], acc[m][n], 0, 0, 0);
        }
    }

    #pragma unroll
    for (int m = 0; m < 2; ++m)
      #pragma unroll
      for (int n = 0; n < 4; ++n)
        #pragma unroll
        for (int r = 0; r < 4; ++r) {
            const int row = h * 64 + wr * 32 + m * 16 + lk * 4 + r;
            const int col = wc * 64 + n * 16 + lr;
            out[((size_t)tile * 128 + row) * BATCH + col] = acc[m][n][r] * 0x1p-16f;
        }
}

// ---------------------------------------------------------------------------
extern "C" void kernel_launch(void* const* d_in, const int* in_sizes, int n_in,
                              void* d_out, int out_size, void* d_ws, size_t ws_size,
                              hipStream_t stream)
{
    const float* x     = (const float*)d_in[0];
    const float* beta0 = (const float*)d_in[1];
    const float* betat = (const float*)d_in[2];
    float* out = (float*)d_out;

    const size_t need_min = 4096 + (size_t)BATCH * TOPIC * 2;   // ~1.05 MB (proven)
    if (ws_size < need_min) return;
    float* s_g  = (float*)d_ws;
    u16*   buf1 = (u16*)((char*)d_ws + 4096);

    const size_t E_OFF = 4u * 1024u * 1024u;
    const bool big = ws_size >= E_OFF + (size_t)VOC * TOPIC * 2;

    hipMemsetAsync(d_ws, 0, 2048, stream);
    cvt_betat_kernel<<<256, 256, 0, stream>>>(betat, buf1);

    if (big) {
        u16* EgW = (u16*)((char*)d_ws + E_OFF);
        gemm1_kernel<<<2000, 512, 0, stream>>>(beta0, buf1, EgW, (size_t)128 * 512, 512, s_g);
        xst_kernel<<<dim3(BATCH / 32, TOPIC / 32), dim3(32, 32), 0, stream>>>(x, s_g, buf1);
        gemm2a_kernel<<<4000, 512, 0, stream>>>(EgW, (size_t)128 * 512, 512, buf1, out, 0, 4);
    } else {
        u16* EgO = (u16*)d_out;
        gemm1_kernel<<<2000, 512, 0, stream>>>(beta0, buf1, EgO, (size_t)262144, 2048, s_g);
        xst_kernel<<<dim3(BATCH / 32, TOPIC / 32), dim3(32, 32), 0, stream>>>(x, s_g, buf1);
        gemm2a_kernel<<<3000, 512, 0, stream>>>(EgO, (size_t)262144, 2048, buf1, out, 256, 3);
        gemm2b_kernel<<<2000, 512, 0, stream>>>(EgO, buf1, out);
    }
}